// Round 9
// baseline (1509.103 us; speedup 1.0000x reference)
//
#include <hip/hip_runtime.h>
#include <hip/hip_bf16.h>

typedef __attribute__((ext_vector_type(8))) short bf16x8;
typedef __attribute__((ext_vector_type(16))) float f32x16;

#define T_TOK 1370
#define DDIM  768
#define SCV   1369   // valid tokens per slab
#define SCP   1408   // s slab padded rows (11*128)
#define MQP   1536   // q padded rows (6*256)
#define NB    8
#define NSLAB 32
#define NST   22     // s supertiles of 256 (4*1408/256)
#define NMT   6      // m tiles of 256

#define MEMFENCE asm volatile("" ::: "memory")
#define BARRIER  do { __builtin_amdgcn_s_barrier(); MEMFENCE; } while (0)
#define VMCNT0   asm volatile("s_waitcnt vmcnt(0)" ::: "memory")

__device__ __forceinline__ unsigned short f2bf(float x) {
  union { __hip_bfloat16 h; unsigned short u; } cv;
  cv.h = __float2bfloat16(x);
  return cv.u;
}

#define GLOAD_LDS16(g, l)                                                     \
  __builtin_amdgcn_global_load_lds(                                           \
      (const __attribute__((address_space(1))) unsigned int*)(g),             \
      (__attribute__((address_space(3))) unsigned int*)(l), 16, 0, 0)

// One block per output row: mean over 3 layers -> l2norm -> bf16 store.
// dst layout: [slabs][pad][768] bf16, rows >= 1369 zeroed. pad via gridDim.x.
extern "C" __global__ __launch_bounds__(192) void prep_kernel(
    const float* __restrict__ src, unsigned short* __restrict__ dst,
    size_t lstride)
{
  const int row  = blockIdx.x;
  const int slab = blockIdx.y;
  const int t    = threadIdx.x;  // 0..191, each owns one float4 (768 = 192*4)
  unsigned short* drow = dst + ((size_t)slab * gridDim.x + row) * DDIM;
  if (row >= SCV) {
    ushort4 z; z.x = z.y = z.z = z.w = 0;
    reinterpret_cast<ushort4*>(drow)[t] = z;
    return;
  }
  const float* base = src + ((size_t)slab * T_TOK + row + 1) * DDIM;
  float4 a = reinterpret_cast<const float4*>(base)[t];
  float4 b = reinterpret_cast<const float4*>(base + lstride)[t];
  float4 c = reinterpret_cast<const float4*>(base + 2 * lstride)[t];
  const float k3 = 1.0f / 3.0f;
  float4 m;
  m.x = (a.x + b.x + c.x) * k3;
  m.y = (a.y + b.y + c.y) * k3;
  m.z = (a.z + b.z + c.z) * k3;
  m.w = (a.w + b.w + c.w) * k3;
  float ss = m.x * m.x + m.y * m.y + m.z * m.z + m.w * m.w;
  #pragma unroll
  for (int d = 1; d < 64; d <<= 1) ss += __shfl_xor(ss, d);
  __shared__ float wsum[3];
  if ((t & 63) == 0) wsum[t >> 6] = ss;
  __syncthreads();
  float tot = wsum[0] + wsum[1] + wsum[2];
  float rn = 1.0f / fmaxf(sqrtf(tot), 1e-12f);
  ushort4 o;
  o.x = f2bf(m.x * rn); o.y = f2bf(m.y * rn);
  o.z = f2bf(m.z * rn); o.w = f2bf(m.w * rn);
  reinterpret_cast<ushort4*>(drow)[t] = o;
}

// 256x256 tile, BK=32, 4 waves (2x2, per-wave 128x128 via 32x32x16 MFMA),
// ring-2 dbuf LDS (64 KB), 2 blocks/CU. part: [8][22][1536] float.
extern "C" __global__ __launch_bounds__(256, 2) void simmax_kernel(
    const unsigned short* __restrict__ xq,
    const unsigned short* __restrict__ xs,
    float* __restrict__ part)
{
  // XCD-chunked bijective remap: nwg = 1056 = 8*132; XCD k owns batch n=k,
  // mt varies fastest so 6 consecutive blocks share one B supertile.
  const int flat = blockIdx.x;
  const int swz  = (flat & 7) * (NMT * NST) + (flat >> 3);
  const int n    = swz / (NMT * NST);
  const int idx  = swz - n * (NMT * NST);
  const int mt   = idx % NMT;
  const int st   = idx / NMT;

  const int tid  = threadIdx.x;
  const int lane = tid & 63;
  const int w    = tid >> 6;    // 0..3
  const int wr   = w >> 1;      // 0..1 (128-row half of 256)
  const int wc   = w & 1;       // 0..1 (128-col half of 256)
  const int l31  = lane & 31;
  const int h    = lane >> 5;

  __shared__ unsigned short ring[2][16384];  // 2 x (A 16KB | B 16KB)
  __shared__ float sfold[512];

  const unsigned short* gA = xq + ((size_t)n * MQP + (size_t)mt * 256) * DDIM;
  const unsigned short* gB = xs + ((size_t)n * 4 * SCP + (size_t)st * 256) * DDIM;

  // staging: A/B each 16 chunks of 1 KB (16 rows x 64 B); wave owns 4 of each.
  // lane -> row c*16+(lane>>2), 16-B slot (lane&3). Source pre-swizzled
  // slot^((row>>1)&3); LDS dest linear; reads XOR the same involution.
  int aoffg[4], aldso[4], boffg[4], bldso[4];
  #pragma unroll
  for (int i = 0; i < 4; ++i) {
    int c = w * 4 + i;
    int r = c * 16 + (lane >> 2);
    int go = r * DDIM + (((lane & 3) ^ ((r >> 1) & 3)) << 3);
    aoffg[i] = go;           aldso[i] = c * 512;
    boffg[i] = go;           bldso[i] = 8192 + c * 512;
  }

  // fragment read byte offsets: row*64 + ((kh*32 + h*16) ^ (((row>>1)&3)<<4));
  // row&31 == l31 for all frags (32-aligned bases).
  const int kx = ((l31 >> 1) & 3) << 4;
  int aoff[4][2], boff[4][2];
  #pragma unroll
  for (int f = 0; f < 4; ++f)
    #pragma unroll
    for (int kh = 0; kh < 2; ++kh) {
      int ko = (kh * 32 + h * 16) ^ kx;
      aoff[f][kh] = (wr * 128 + f * 32 + l31) * 64 + ko;
      boff[f][kh] = 16384 + (wc * 128 + f * 32 + l31) * 64 + ko;
    }

  f32x16 acc[4][4];
  {
    f32x16 zz = {0.f,0.f,0.f,0.f,0.f,0.f,0.f,0.f,
                 0.f,0.f,0.f,0.f,0.f,0.f,0.f,0.f};
    #pragma unroll
    for (int a = 0; a < 4; ++a)
      #pragma unroll
      for (int b = 0; b < 4; ++b) acc[a][b] = zz;
  }

  #define ISSUE(KT, RB)                                                       \
    do {                                                                      \
      const unsigned short* ga_ = gA + (KT) * 32;                             \
      const unsigned short* gb_ = gB + (KT) * 32;                             \
      unsigned short* lb_ = ring[RB];                                         \
      _Pragma("unroll") for (int i = 0; i < 4; ++i)                           \
        GLOAD_LDS16(ga_ + aoffg[i], lb_ + aldso[i]);                          \
      _Pragma("unroll") for (int i = 0; i < 4; ++i)                           \
        GLOAD_LDS16(gb_ + boffg[i], lb_ + bldso[i]);                          \
    } while (0)

  ISSUE(0, 0);
  VMCNT0;
  BARRIER;

  for (int kt = 0; kt < 24; ++kt) {
    if (kt + 1 < 24) ISSUE(kt + 1, (kt + 1) & 1);

    const char* Cb = reinterpret_cast<const char*>(ring[kt & 1]);
    #pragma unroll
    for (int kh = 0; kh < 2; ++kh) {
      bf16x8 af[4], bfv[4];
      #pragma unroll
      for (int f = 0; f < 4; ++f) {
        af[f]  = *reinterpret_cast<const bf16x8*>(Cb + aoff[f][kh]);
        bfv[f] = *reinterpret_cast<const bf16x8*>(Cb + boff[f][kh]);
      }
      __builtin_amdgcn_s_setprio(1);
      #pragma unroll
      for (int mf = 0; mf < 4; ++mf)
        #pragma unroll
        for (int nf = 0; nf < 4; ++nf)
          acc[mf][nf] = __builtin_amdgcn_mfma_f32_32x32x16_bf16(
              af[mf], bfv[nf], acc[mf][nf], 0, 0, 0);
      __builtin_amdgcn_s_setprio(0);
    }

    if (kt + 1 < 24) VMCNT0;   // next buffer landed (issued ~a full step ago)
    if (kt < 23) BARRIER;
  }

  // ---- epilogue: masked fold over cols, butterfly over 32 col-lanes ----
  // C frag: col = nf*32 + l31 (+ wc*128 + st*256), row = (j&3)+8*(j>>2)+4*h.
  bool colv[4];
  #pragma unroll
  for (int nf = 0; nf < 4; ++nf) {
    int col = st * 256 + wc * 128 + nf * 32 + l31;   // 0..5631
    int within = col - (col / SCP) * SCP;
    colv[nf] = within < SCV;
  }

  float rm[4][16];
  #pragma unroll
  for (int mf = 0; mf < 4; ++mf)
    #pragma unroll
    for (int j = 0; j < 16; ++j) {
      float v = -1e30f;
      #pragma unroll
      for (int nf = 0; nf < 4; ++nf)
        if (colv[nf]) v = fmaxf(v, acc[mf][nf][j]);
      rm[mf][j] = v;
    }

  #pragma unroll
  for (int msk = 1; msk < 32; msk <<= 1)
    #pragma unroll
    for (int mf = 0; mf < 4; ++mf)
      #pragma unroll
      for (int j = 0; j < 16; ++j)
        rm[mf][j] = fmaxf(rm[mf][j], __shfl_xor(rm[mf][j], msk));

  __syncthreads();
  if (l31 == 0) {
    #pragma unroll
    for (int mf = 0; mf < 4; ++mf)
      #pragma unroll
      for (int j = 0; j < 16; ++j) {
        int r = wr * 128 + mf * 32 + (j & 3) + 8 * (j >> 2) + 4 * h;
        sfold[wc * 256 + r] = rm[mf][j];
      }
  }
  __syncthreads();
  if (tid < 256) {
    float v = fmaxf(sfold[tid], sfold[256 + tid]);
    part[((size_t)n * NST + st) * MQP + (size_t)mt * 256 + tid] = v;
  }
}

extern "C" __global__ void finalize_kernel(const float* __restrict__ part,
                                           float* __restrict__ out) {
  int i = blockIdx.x * 256 + threadIdx.x;
  if (i >= NB * SCV) return;
  int n = i / SCV, q = i - n * SCV;
  const float* p = part + (size_t)n * NST * MQP + q;
  float m = p[0];
  #pragma unroll 4
  for (int g = 1; g < NST; ++g) m = fmaxf(m, p[(size_t)g * MQP]);
  out[i] = 1.0f - m;
}

extern "C" void kernel_launch(void* const* d_in, const int* in_sizes, int n_in,
                              void* d_out, int out_size, void* d_ws, size_t ws_size,
                              hipStream_t stream) {
  const float* q_feats = (const float*)d_in[0];  // (3, 8, 1370, 768) f32
  const float* s_feats = (const float*)d_in[1];  // (3, 32, 1370, 768) f32
  float* out = (float*)d_out;                    // (8, 1, 37, 37) f32

  char* ws = (char*)d_ws;
  const size_t xq_bytes = (size_t)NB * MQP * DDIM * 2;     // 18,874,368
  const size_t xs_bytes = (size_t)NSLAB * SCP * DDIM * 2;  // 69,206,016
  unsigned short* xq = (unsigned short*)ws;
  unsigned short* xs = (unsigned short*)(ws + xq_bytes);
  float* part        = (float*)(ws + xq_bytes + xs_bytes); // 8*22*1536 floats

  prep_kernel<<<dim3(MQP, NB), 192, 0, stream>>>(
      q_feats, xq, (size_t)NB * T_TOK * DDIM);
  prep_kernel<<<dim3(SCP, NSLAB), 192, 0, stream>>>(
      s_feats, xs, (size_t)NSLAB * T_TOK * DDIM);
  simmax_kernel<<<dim3(NB * NMT * NST), 256, 0, stream>>>(xq, xs, part);
  finalize_kernel<<<dim3((NB * SCV + 255) / 256), 256, 0, stream>>>(part, out);
}

// Round 10
// 208.739 us; speedup vs baseline: 7.2296x; 7.2296x over previous
//
#include <hip/hip_runtime.h>
#include <hip/hip_bf16.h>

typedef __attribute__((ext_vector_type(4))) float f32x4;

#define T_TOK 1370
#define DDIM  768
#define SCV   1369   // valid tokens per slab
#define SCP   1408   // s slab padded rows (11*128)
#define MQP   1536   // q padded rows (6*256)
#define NB    8
#define NSLAB 32
#define NST   44     // s tiles of 128 (4 slabs * 11)
#define NMT   6      // m tiles of 256

#define MEMFENCE asm volatile("" ::: "memory")
#define BARRIER  do { __builtin_amdgcn_s_barrier(); MEMFENCE; } while (0)

#define GLOAD_LDS16(g, l)                                                     \
  __builtin_amdgcn_global_load_lds(                                           \
      (const __attribute__((address_space(1))) unsigned int*)(g),             \
      (__attribute__((address_space(3))) unsigned int*)(l), 16, 0, 0)

// One block per output row: mean over 3 layers -> l2norm -> fp8 e4m3 store.
// dst layout: [slabs][pad][768] fp8, rows >= 1369 zeroed. pad via gridDim.x.
extern "C" __global__ __launch_bounds__(192) void prep_kernel(
    const float* __restrict__ src, unsigned char* __restrict__ dst,
    size_t lstride)
{
  const int row  = blockIdx.x;
  const int slab = blockIdx.y;
  const int t    = threadIdx.x;  // 0..191, each owns one float4 (768 = 192*4)
  unsigned char* drow = dst + ((size_t)slab * gridDim.x + row) * DDIM;
  if (row >= SCV) {
    reinterpret_cast<unsigned int*>(drow)[t] = 0u;
    return;
  }
  const float* base = src + ((size_t)slab * T_TOK + row + 1) * DDIM;
  float4 a = reinterpret_cast<const float4*>(base)[t];
  float4 b = reinterpret_cast<const float4*>(base + lstride)[t];
  float4 c = reinterpret_cast<const float4*>(base + 2 * lstride)[t];
  const float k3 = 1.0f / 3.0f;
  float4 m;
  m.x = (a.x + b.x + c.x) * k3;
  m.y = (a.y + b.y + c.y) * k3;
  m.z = (a.z + b.z + c.z) * k3;
  m.w = (a.w + b.w + c.w) * k3;
  float ss = m.x * m.x + m.y * m.y + m.z * m.z + m.w * m.w;
  #pragma unroll
  for (int d = 1; d < 64; d <<= 1) ss += __shfl_xor(ss, d);
  __shared__ float wsum[3];
  if ((t & 63) == 0) wsum[t >> 6] = ss;
  __syncthreads();
  float tot = wsum[0] + wsum[1] + wsum[2];
  float rn = 1.0f / fmaxf(sqrtf(tot), 1e-12f);
  int pk = __builtin_amdgcn_cvt_pk_fp8_f32(m.x * rn, m.y * rn, 0, false);
  pk = __builtin_amdgcn_cvt_pk_fp8_f32(m.z * rn, m.w * rn, pk, true);
  reinterpret_cast<unsigned int*>(drow)[t] = (unsigned int)pk;
}

// 256x128 tile, BK=32, fp8 e4m3, 4 waves (2Mx2N, per-wave 128x64), ring-3
// LDS (36 KB), counted vmcnt(3), 2 blocks/CU. part: [8][44][1536] float.
extern "C" __global__ __launch_bounds__(256, 2) void simmax_kernel(
    const unsigned char* __restrict__ xq,
    const unsigned char* __restrict__ xs,
    float* __restrict__ part)
{
  // XCD-chunked bijective remap: nwg = 2112 = 8*264; XCD k owns batch n=k,
  // mt varies fastest so 6 consecutive blocks share one B s-tile.
  const int flat = blockIdx.x + NMT * (blockIdx.y + NST * blockIdx.z);
  const int swz  = (flat & 7) * (NMT * NST) + (flat >> 3);
  const int mt   = swz % NMT;
  const int st   = (swz / NMT) % NST;
  const int n    = swz / (NMT * NST);

  const int tid = threadIdx.x;
  const int lane = tid & 63;
  const int w    = tid >> 6;    // 0..3
  const int wr = w >> 1;        // 0..1 (128-row band of 256)
  const int wc = w & 1;         // 0..1 (64-col half of 128)
  const int l15 = lane & 15, l4 = lane >> 4;

  // ring: [3] x (A 256x32 | B 128x32) fp8 = 3 x 12 KB = 36 KB
  __shared__ unsigned char ring[3][12288];

  const int slab = st / 11;
  const int lt   = st - slab * 11;
  const unsigned char* gA = xq + ((size_t)n * MQP + (size_t)mt * 256) * DDIM;
  const unsigned char* gB =
      xs + ((size_t)(n * 4 + slab) * SCP + (size_t)lt * 128) * DDIM;

  // staging: 1-KB chunks = 32 rows x 32 B. A = 8 chunks (wave owns w*2..+1),
  // B = 4 chunks (wave owns chunk w). lane -> row c*32+(lane>>1), 16-B slot
  // (lane&1). Source pre-swizzled slot^((row>>2)&1); LDS dest linear; reads
  // XOR the same involution (16-B granularity) => <=2-way conflicts (free).
  int aoffg[2], aldso[2], boffg0, bldso0;
  #pragma unroll
  for (int i = 0; i < 2; ++i) {
    int c = w * 2 + i;
    int r = c * 32 + (lane >> 1);
    aoffg[i] = r * DDIM + (((lane & 1) ^ ((r >> 2) & 1)) << 4);
    aldso[i] = c * 1024;
  }
  {
    int r = w * 32 + (lane >> 1);
    boffg0 = r * DDIM + (((lane & 1) ^ ((r >> 2) & 1)) << 4);
    bldso0 = 8192 + w * 1024;   // B region starts at 8 KB
  }

  // fragment read byte offsets: row*32 + kxor, rows are 16-aligned per frag
  // so (row>>2)&1 == (l15>>2)&1 lane-invariantly.
  const int kxor = (((l4 >> 1) ^ ((l15 >> 2) & 1)) << 4) + (l4 & 1) * 8;
  int aoff[8], boff[4];
  #pragma unroll
  for (int mf = 0; mf < 8; ++mf)
    aoff[mf] = (wr * 128 + mf * 16 + l15) * 32 + kxor;
  #pragma unroll
  for (int nf = 0; nf < 4; ++nf)
    boff[nf] = 8192 + (wc * 64 + nf * 16 + l15) * 32 + kxor;

  f32x4 acc[8][4];
  {
    f32x4 zz = {0.f, 0.f, 0.f, 0.f};
    #pragma unroll
    for (int a = 0; a < 8; ++a)
      #pragma unroll
      for (int b = 0; b < 4; ++b) acc[a][b] = zz;
  }

  #define ISSUE(KT, RB)                                                      \
    do {                                                                     \
      const unsigned char* ga_ = gA + (KT) * 32;                             \
      const unsigned char* gb_ = gB + (KT) * 32;                             \
      unsigned char* lb_ = ring[RB];                                         \
      _Pragma("unroll") for (int i = 0; i < 2; ++i)                          \
        GLOAD_LDS16(ga_ + aoffg[i], lb_ + aldso[i]);                         \
      GLOAD_LDS16(gb_ + boffg0, lb_ + bldso0);                               \
    } while (0)

  // prologue: fill pipeline 2 deep (3 loads/wave per step)
  ISSUE(0, 0);
  ISSUE(1, 1);
  asm volatile("s_waitcnt vmcnt(3)" ::: "memory");  // kt0 landed, kt1 flying
  BARRIER;

  for (int kt = 0; kt < 24; ++kt) {
    if (kt + 2 < 24) ISSUE(kt + 2, (kt + 2) % 3);

    const char* Cb = reinterpret_cast<const char*>(ring[kt % 3]);
    long bfr[4], af[8];
    #pragma unroll
    for (int nf = 0; nf < 4; ++nf)
      bfr[nf] = *reinterpret_cast<const long*>(Cb + boff[nf]);
    #pragma unroll
    for (int mf = 0; mf < 8; ++mf)
      af[mf] = *reinterpret_cast<const long*>(Cb + aoff[mf]);

    __builtin_amdgcn_s_setprio(1);
    #pragma unroll
    for (int mf = 0; mf < 8; ++mf)
      #pragma unroll
      for (int nf = 0; nf < 4; ++nf)
        acc[mf][nf] = __builtin_amdgcn_mfma_f32_16x16x32_fp8_fp8(
            af[mf], bfr[nf], acc[mf][nf], 0, 0, 0);
    __builtin_amdgcn_s_setprio(0);

    // wait for NEXT buffer's batch (issued a full K-step ago); keep the
    // just-issued 3 in flight across the barrier.
    if (kt < 22)       asm volatile("s_waitcnt vmcnt(3)" ::: "memory");
    else if (kt == 22) asm volatile("s_waitcnt vmcnt(0)" ::: "memory");
    if (kt < 23) BARRIER;
  }

  // ---- epilogue: masked running max, butterfly, cross-wave combine
  float rmax[8][4];
  #pragma unroll
  for (int a = 0; a < 8; ++a)
    #pragma unroll
    for (int b = 0; b < 4; ++b) rmax[a][b] = -1e30f;

  #pragma unroll
  for (int nf = 0; nf < 4; ++nf) {
    int col = lt * 128 + wc * 64 + nf * 16 + l15;
    if (col < SCV) {
      #pragma unroll
      for (int mf = 0; mf < 8; ++mf)
        #pragma unroll
        for (int j = 0; j < 4; ++j)
          rmax[mf][j] = fmaxf(rmax[mf][j], acc[mf][nf][j]);
    }
  }

  #pragma unroll
  for (int msk = 1; msk < 16; msk <<= 1)
    #pragma unroll
    for (int mf = 0; mf < 8; ++mf)
      #pragma unroll
      for (int j = 0; j < 4; ++j)
        rmax[mf][j] = fmaxf(rmax[mf][j], __shfl_xor(rmax[mf][j], msk));

  __syncthreads();
  float* buf = reinterpret_cast<float*>(&ring[0][0]);  // 2 x 256 floats
  if (l15 == 0) {
    #pragma unroll
    for (int mf = 0; mf < 8; ++mf)
      #pragma unroll
      for (int j = 0; j < 4; ++j) {
        int r = wr * 128 + mf * 16 + l4 * 4 + j;   // 0..255
        buf[wc * 256 + r] = rmax[mf][j];
      }
  }
  __syncthreads();
  if (tid < 256) {
    float v = fmaxf(buf[tid], buf[256 + tid]);
    part[((size_t)n * NST + st) * MQP + (size_t)mt * 256 + tid] = v;
  }
}

extern "C" __global__ void finalize_kernel(const float* __restrict__ part,
                                           float* __restrict__ out) {
  int i = blockIdx.x * 256 + threadIdx.x;
  if (i >= NB * SCV) return;
  int n = i / SCV, q = i - n * SCV;
  const float* p = part + (size_t)n * NST * MQP + q;
  float m = p[0];
  #pragma unroll 4
  for (int g = 1; g < NST; ++g) m = fmaxf(m, p[(size_t)g * MQP]);
  out[i] = 1.0f - m;
}

extern "C" void kernel_launch(void* const* d_in, const int* in_sizes, int n_in,
                              void* d_out, int out_size, void* d_ws, size_t ws_size,
                              hipStream_t stream) {
  const float* q_feats = (const float*)d_in[0];  // (3, 8, 1370, 768) f32
  const float* s_feats = (const float*)d_in[1];  // (3, 32, 1370, 768) f32
  float* out = (float*)d_out;                    // (8, 1, 37, 37) f32

  char* ws = (char*)d_ws;
  const size_t xq_bytes = (size_t)NB * MQP * DDIM;     // 9,437,184 (fp8)
  const size_t xs_bytes = (size_t)NSLAB * SCP * DDIM;  // 34,603,008 (fp8)
  unsigned char* xq = (unsigned char*)ws;
  unsigned char* xs = (unsigned char*)(ws + xq_bytes);
  float* part       = (float*)(ws + xq_bytes + xs_bytes); // 8*44*1536 floats

  prep_kernel<<<dim3(MQP, NB), 192, 0, stream>>>(
      q_feats, xq, (size_t)NB * T_TOK * DDIM);
  prep_kernel<<<dim3(SCP, NSLAB), 192, 0, stream>>>(
      s_feats, xs, (size_t)NSLAB * T_TOK * DDIM);
  simmax_kernel<<<dim3(NMT, NST, NB), 256, 0, stream>>>(xq, xs, part);
  finalize_kernel<<<dim3((NB * SCV + 255) / 256), 256, 0, stream>>>(part, out);
}

// Round 11
// 181.154 us; speedup vs baseline: 8.3305x; 1.1523x over previous
//
#include <hip/hip_runtime.h>
#include <hip/hip_bf16.h>

typedef __attribute__((ext_vector_type(4))) float f32x4;
typedef __attribute__((ext_vector_type(8))) int i32x8;

#define T_TOK 1370
#define DDIM  768
#define SCV   1369   // valid tokens per slab
#define SCP   1408   // s slab padded rows (11*128)
#define MQP   1536   // q padded rows (6*256)
#define NB    8
#define NSLAB 32
#define NST   22     // s supertiles of 256 (4*1408/256)
#define NMT   6      // m tiles of 256

#define MEMFENCE asm volatile("" ::: "memory")
#define BARRIER  do { __builtin_amdgcn_s_barrier(); MEMFENCE; } while (0)
#define VMCNT0   asm volatile("s_waitcnt vmcnt(0)" ::: "memory")

#define GLOAD_LDS16(g, l)                                                     \
  __builtin_amdgcn_global_load_lds(                                           \
      (const __attribute__((address_space(1))) unsigned int*)(g),             \
      (__attribute__((address_space(3))) unsigned int*)(l), 16, 0, 0)

// One block per output row: mean over 3 layers -> l2norm -> fp8 e4m3 store.
// dst layout: [slabs][pad][768] fp8, rows >= 1369 zeroed. pad via gridDim.x.
extern "C" __global__ __launch_bounds__(192) void prep_kernel(
    const float* __restrict__ src, unsigned char* __restrict__ dst,
    size_t lstride)
{
  const int row  = blockIdx.x;
  const int slab = blockIdx.y;
  const int t    = threadIdx.x;  // 0..191, each owns one float4 (768 = 192*4)
  unsigned char* drow = dst + ((size_t)slab * gridDim.x + row) * DDIM;
  if (row >= SCV) {
    reinterpret_cast<unsigned int*>(drow)[t] = 0u;
    return;
  }
  const float* base = src + ((size_t)slab * T_TOK + row + 1) * DDIM;
  float4 a = reinterpret_cast<const float4*>(base)[t];
  float4 b = reinterpret_cast<const float4*>(base + lstride)[t];
  float4 c = reinterpret_cast<const float4*>(base + 2 * lstride)[t];
  const float k3 = 1.0f / 3.0f;
  float4 m;
  m.x = (a.x + b.x + c.x) * k3;
  m.y = (a.y + b.y + c.y) * k3;
  m.z = (a.z + b.z + c.z) * k3;
  m.w = (a.w + b.w + c.w) * k3;
  float ss = m.x * m.x + m.y * m.y + m.z * m.z + m.w * m.w;
  #pragma unroll
  for (int d = 1; d < 64; d <<= 1) ss += __shfl_xor(ss, d);
  __shared__ float wsum[3];
  if ((t & 63) == 0) wsum[t >> 6] = ss;
  __syncthreads();
  float tot = wsum[0] + wsum[1] + wsum[2];
  float rn = 1.0f / fmaxf(sqrtf(tot), 1e-12f);
  int pk = __builtin_amdgcn_cvt_pk_fp8_f32(m.x * rn, m.y * rn, 0, false);
  pk = __builtin_amdgcn_cvt_pk_fp8_f32(m.z * rn, m.w * rn, pk, true);
  reinterpret_cast<unsigned int*>(drow)[t] = (unsigned int)pk;
}

// 256x256 tile, BK=128, MX-fp8 (scale=1.0) 16x16x128 MFMA, 8 waves
// (2M x 4N, per-wave 128x64), dbuf LDS 2x64 KB, 6 K-steps.
// Grid 1056 = 8 XCD-chunks x 132. part: [8][22][1536] float.
extern "C" __global__ __launch_bounds__(512, 2) void simmax_kernel(
    const unsigned char* __restrict__ xq,
    const unsigned char* __restrict__ xs,
    float* __restrict__ part)
{
  // XCD-chunked bijective remap: nwg = 1056 = 8*132; XCD k owns batch n=k,
  // mt varies fastest so 6 consecutive blocks share one B supertile.
  const int flat = blockIdx.x;
  const int swz  = (flat & 7) * (NMT * NST) + (flat >> 3);
  const int n    = swz / (NMT * NST);
  const int idx  = swz - n * (NMT * NST);
  const int mt   = idx % NMT;
  const int st   = idx / NMT;

  const int tid  = threadIdx.x;  // 0..511
  const int lane = tid & 63;
  const int w    = tid >> 6;     // 0..7
  const int wr   = w >> 2;       // 0..1 : 128-row half of 256
  const int wcn  = w & 3;        // 0..3 : 64-col quarter of 256
  const int l15  = lane & 15, l4 = lane >> 4;

  // dbuf: [2] x (A 256x128B = 32 KB | B 256x128B = 32 KB) = 128 KB
  __shared__ unsigned char ring[2][65536];
  __shared__ float sfold[1024];

  const unsigned char* gA = xq + ((size_t)n * MQP + (size_t)mt * 256) * DDIM;
  const unsigned char* gB = xs + ((size_t)n * 4 * SCP + (size_t)st * 256) * DDIM;

  // staging: A and B each 32 chunks of 1 KB (8 rows x 128 B); wave owns
  // chunks w*4..+3 of each. lane -> row c*8+(lane>>3), 16-B slot lane&7.
  // Source pre-swizzled slot^(row&7); LDS dest linear (c*1024 + lane*16);
  // reads XOR the same involution. Same goff serves A and B.
  int goff[4], ldso[4];
  #pragma unroll
  for (int i = 0; i < 4; ++i) {
    int c = w * 4 + i;
    int r = c * 8 + (lane >> 3);
    goff[i] = r * DDIM + (((lane & 7) ^ (r & 7)) << 4);
    ldso[i] = c * 1024;
  }

  // fragment read byte offsets: lane covers row (l15-based), 32 B at
  // k0 = l4*32 -> two b128 at slot (2*l4)^(row&7) and that ^16.
  int aoff[8], boff[4];
  #pragma unroll
  for (int mf = 0; mf < 8; ++mf) {
    int row = wr * 128 + mf * 16 + l15;
    aoff[mf] = row * 128 + ((((l4 << 1) ^ (row & 7))) << 4);
  }
  #pragma unroll
  for (int nf = 0; nf < 4; ++nf) {
    int row = wcn * 64 + nf * 16 + l15;
    boff[nf] = 32768 + row * 128 + ((((l4 << 1) ^ (row & 7))) << 4);
  }

  f32x4 acc[8][4];
  {
    f32x4 zz = {0.f, 0.f, 0.f, 0.f};
    #pragma unroll
    for (int a = 0; a < 8; ++a)
      #pragma unroll
      for (int b = 0; b < 4; ++b) acc[a][b] = zz;
  }

  #define ISSUE(KT, RB)                                                      \
    do {                                                                     \
      const unsigned char* ga_ = gA + (KT) * 128;                            \
      const unsigned char* gb_ = gB + (KT) * 128;                            \
      unsigned char* la_ = ring[RB];                                         \
      unsigned char* lb_ = ring[RB] + 32768;                                 \
      _Pragma("unroll") for (int i = 0; i < 4; ++i)                          \
        GLOAD_LDS16(ga_ + goff[i], la_ + ldso[i]);                           \
      _Pragma("unroll") for (int i = 0; i < 4; ++i)                          \
        GLOAD_LDS16(gb_ + goff[i], lb_ + ldso[i]);                           \
    } while (0)

  ISSUE(0, 0);
  VMCNT0;
  BARRIER;

  for (int kt = 0; kt < 6; ++kt) {
    if (kt + 1 < 6) ISSUE(kt + 1, (kt + 1) & 1);

    const char* Cb = reinterpret_cast<const char*>(ring[kt & 1]);
    i32x8 bfr[4];
    #pragma unroll
    for (int nf = 0; nf < 4; ++nf) {
      int4 lo = *reinterpret_cast<const int4*>(Cb + boff[nf]);
      int4 hi = *reinterpret_cast<const int4*>(Cb + (boff[nf] ^ 16));
      bfr[nf] = i32x8{lo.x, lo.y, lo.z, lo.w, hi.x, hi.y, hi.z, hi.w};
    }
    __builtin_amdgcn_s_setprio(1);
    #pragma unroll
    for (int mf = 0; mf < 8; ++mf) {
      int4 lo = *reinterpret_cast<const int4*>(Cb + aoff[mf]);
      int4 hi = *reinterpret_cast<const int4*>(Cb + (aoff[mf] ^ 16));
      i32x8 af = i32x8{lo.x, lo.y, lo.z, lo.w, hi.x, hi.y, hi.z, hi.w};
      #pragma unroll
      for (int nf = 0; nf < 4; ++nf)
        acc[mf][nf] = __builtin_amdgcn_mfma_scale_f32_16x16x128_f8f6f4(
            af, bfr[nf], acc[mf][nf], 0, 0, 0, 127, 0, 127);
    }
    __builtin_amdgcn_s_setprio(0);

    if (kt + 1 < 6) VMCNT0;   // next buffer landed (issued a full step ago)
    if (kt < 5) BARRIER;
  }

  // ---- epilogue: masked running max, butterfly over 16 col-lanes ----
  bool colv[4];
  #pragma unroll
  for (int nf = 0; nf < 4; ++nf) {
    int col = st * 256 + wcn * 64 + nf * 16 + l15;   // 0..5631
    int within = col - (col / SCP) * SCP;
    colv[nf] = within < SCV;
  }

  float rm[8][4];
  #pragma unroll
  for (int mf = 0; mf < 8; ++mf)
    #pragma unroll
    for (int j = 0; j < 4; ++j) {
      float v = -1e30f;
      #pragma unroll
      for (int nf = 0; nf < 4; ++nf)
        if (colv[nf]) v = fmaxf(v, acc[mf][nf][j]);
      rm[mf][j] = v;
    }

  #pragma unroll
  for (int msk = 1; msk < 16; msk <<= 1)
    #pragma unroll
    for (int mf = 0; mf < 8; ++mf)
      #pragma unroll
      for (int j = 0; j < 4; ++j)
        rm[mf][j] = fmaxf(rm[mf][j], __shfl_xor(rm[mf][j], msk));

  __syncthreads();
  if (l15 == 0) {
    #pragma unroll
    for (int mf = 0; mf < 8; ++mf)
      #pragma unroll
      for (int j = 0; j < 4; ++j) {
        int r = wr * 128 + mf * 16 + l4 * 4 + j;   // 0..255
        sfold[wcn * 256 + r] = rm[mf][j];
      }
  }
  __syncthreads();
  if (tid < 256) {
    float v = fmaxf(fmaxf(sfold[tid], sfold[256 + tid]),
                    fmaxf(sfold[512 + tid], sfold[768 + tid]));
    part[((size_t)n * NST + st) * MQP + (size_t)mt * 256 + tid] = v;
  }
}

extern "C" __global__ void finalize_kernel(const float* __restrict__ part,
                                           float* __restrict__ out) {
  int i = blockIdx.x * 256 + threadIdx.x;
  if (i >= NB * SCV) return;
  int n = i / SCV, q = i - n * SCV;
  const float* p = part + (size_t)n * NST * MQP + q;
  float m = p[0];
  #pragma unroll 4
  for (int g = 1; g < NST; ++g) m = fmaxf(m, p[(size_t)g * MQP]);
  out[i] = 1.0f - m;
}

extern "C" void kernel_launch(void* const* d_in, const int* in_sizes, int n_in,
                              void* d_out, int out_size, void* d_ws, size_t ws_size,
                              hipStream_t stream) {
  const float* q_feats = (const float*)d_in[0];  // (3, 8, 1370, 768) f32
  const float* s_feats = (const float*)d_in[1];  // (3, 32, 1370, 768) f32
  float* out = (float*)d_out;                    // (8, 1, 37, 37) f32

  char* ws = (char*)d_ws;
  const size_t xq_bytes = (size_t)NB * MQP * DDIM;     // 9,437,184 (fp8)
  const size_t xs_bytes = (size_t)NSLAB * SCP * DDIM;  // 34,603,008 (fp8)
  unsigned char* xq = (unsigned char*)ws;
  unsigned char* xs = (unsigned char*)(ws + xq_bytes);
  float* part       = (float*)(ws + xq_bytes + xs_bytes); // 8*22*1536 floats

  prep_kernel<<<dim3(MQP, NB), 192, 0, stream>>>(
      q_feats, xq, (size_t)NB * T_TOK * DDIM);
  prep_kernel<<<dim3(SCP, NSLAB), 192, 0, stream>>>(
      s_feats, xs, (size_t)NSLAB * T_TOK * DDIM);
  simmax_kernel<<<dim3(NB * NMT * NST), 512, 0, stream>>>(xq, xs, part);
  finalize_kernel<<<dim3((NB * SCV + 255) / 256), 256, 0, stream>>>(part, out);
}